// Round 3
// baseline (258.453 us; speedup 1.0000x reference)
//
#include <hip/hip_runtime.h>

// SSIM map — wave-autonomous rolling-register kernel, barrier-free.
// B=16, C=3, H=W=512, 11-tap separable gaussian (sigma=1.5).
//
// One wave produces a 64-col x 64-row output band, marching down input rows
// with a depth-1 software pipeline. Per row: 4 prefetched global loads
// (64 cols + 10 halo cols, x and y) -> private 74-entry float2 LDS line
// buffer -> horizontal 11-tap conv of 5 fields in registers -> vertical
// 11-tap conv via 11x5 rolling register accumulators (static mod-11 slot
// indexing from the unrolled 11-phase loop) -> SSIM epilogue with rcp.
//
// NO __syncthreads anywhere: waves in a block are fully independent, each
// owns its LDS slice. Within a wave DS ops execute in order; we emit
// s_waitcnt lgkmcnt(0) + wave_barrier between LDS write and read. This keeps
// global loads in flight across rows (no vmcnt(0) drain per row, which was
// round 2's 163us latency trap).

#define W    512
#define H    512
#define BC   48
#define RPB  64           // output rows per wave
#define NS   (W / 64)     // 8 col strips
#define NB   (H / RPB)    // 8 row bands
#define WPB  4            // independent waves per block

__global__ __launch_bounds__(256) void ssim_kernel(
    const float* __restrict__ x, const float* __restrict__ y,
    float* __restrict__ out)
{
    __shared__ float2 buf[WPB][80];   // per-wave 74-entry line buffer (2.5 KB)

    // fp32-normalized gaussian, sigma=1.5, K=11 (matches np reference ~1e-7)
    const float g[11] = {
        0.00102838f, 0.00759875f, 0.03600077f, 0.10936069f, 0.21300553f,
        0.26601172f,
        0.21300553f, 0.10936069f, 0.03600077f, 0.00759875f, 0.00102838f};

    const int tid   = threadIdx.x;
    const int lane  = tid & 63;
    const int wid   = tid >> 6;
    const int strip = blockIdx.x;                 // 0..7
    const int band  = blockIdx.y * WPB + wid;     // 0..7
    const int bc    = blockIdx.z;                 // 0..47

    const int col0 = strip * 64;
    const int r0   = band * RPB;

    const float* __restrict__ xp = x + (size_t)bc * H * W;
    const float* __restrict__ yp = y + (size_t)bc * H * W;
    float* __restrict__ op = out + (size_t)bc * H * W + col0 + lane;

    const int  gc   = col0 - 5 + lane;            // this lane's load col
    const bool cok  = (gc >= 0) && (gc < W);
    const bool cok2 = (lane < 10) && (gc + 64 < W);

    float2* __restrict__ lb = buf[wid];

    // rolling vertical accumulators: slot j holds the in-flight output row
    // with (o - r0 + 5) mod 11 == j; 5 fields each
    float acc[11][5];
#pragma unroll
    for (int j = 0; j < 11; ++j)
#pragma unroll
        for (int f = 0; f < 5; ++f) acc[j][f] = 0.f;

    auto loadrow = [&](int rr, float& vx, float& vy, float& vx2, float& vy2) {
        vx = vy = vx2 = vy2 = 0.f;
        const int r = r0 - 5 + rr;
        if (rr < 74 && r >= 0 && r < H) {         // wave-uniform branch
            const float* __restrict__ xr = xp + (size_t)r * W + gc;
            const float* __restrict__ yr = yp + (size_t)r * W + gc;
            if (cok)  { vx  = xr[0];  vy  = yr[0];  }
            if (cok2) { vx2 = xr[64]; vy2 = yr[64]; }
        }
    };

    float cvx, cvy, cvx2, cvy2;     // current row (being consumed)
    float nvx, nvy, nvx2, nvy2;     // next row (in flight)
    loadrow(0, cvx, cvy, cvx2, cvy2);

    // input rows rr = 0..73  ->  r = r0-5 .. r0+68
#pragma unroll 1
    for (int outer = 0; outer < 7; ++outer) {
#pragma unroll
        for (int ph = 0; ph < 11; ++ph) {
            const int rr = outer * 11 + ph;
            if (rr < 74) {                        // wave-uniform guard
                // prefetch next row (loads stay in flight through compute)
                loadrow(rr + 1, nvx, nvy, nvx2, nvy2);

                // stage current row into the private LDS line buffer
                lb[lane] = make_float2(cvx, cvy);
                if (lane < 10) lb[64 + lane] = make_float2(cvx2, cvy2);
                __builtin_amdgcn_s_waitcnt(0xC07F);   // lgkmcnt(0) only
                __builtin_amdgcn_wave_barrier();

                // horizontal 11-tap conv at output col col0+lane
                float hx = 0.f, hy = 0.f, hxx = 0.f, hyy = 0.f, hxy = 0.f;
#pragma unroll
                for (int k = 0; k < 11; ++k) {
                    const float  w = g[k];
                    const float2 a = lb[lane + k];
                    hx  += w * a.x;
                    hy  += w * a.y;
                    hxx += w * (a.x * a.x);
                    hyy += w * (a.y * a.y);
                    hxy += w * (a.x * a.y);
                }
                __builtin_amdgcn_wave_barrier();  // keep next writes after reads

                // vertical accumulate into all 11 pending output rows:
                // slot j gets weight g[(ph - j + 16) % 11]
#pragma unroll
                for (int j = 0; j < 11; ++j) {
                    const int   m = (ph - j + 16) % 11;
                    const float w = g[m];
                    acc[j][0] += w * hx;
                    acc[j][1] += w * hy;
                    acc[j][2] += w * hxx;
                    acc[j][3] += w * hyy;
                    acc[j][4] += w * hxy;
                }

                // slot (ph+6)%11 just received its last tap: output row rr-10
                const int jc = (ph + 6) % 11;
                if (rr >= 10) {
                    const float mu1   = acc[jc][0];
                    const float mu2   = acc[jc][1];
                    const float mu1sq = mu1 * mu1;
                    const float mu2sq = mu2 * mu2;
                    const float mu12  = mu1 * mu2;
                    const float s1    = acc[jc][2] - mu1sq;
                    const float s2    = acc[jc][3] - mu2sq;
                    const float s12   = acc[jc][4] - mu12;
                    const float num = (2.f * mu12 + 1e-4f) * (2.f * s12 + 9e-4f);
                    const float den = (mu1sq + mu2sq + 1e-4f) * (s1 + s2 + 9e-4f);
                    op[(size_t)(r0 + rr - 10) * W] = num * __builtin_amdgcn_rcpf(den);
                }
#pragma unroll
                for (int f = 0; f < 5; ++f) acc[jc][f] = 0.f;

                // rotate pipeline registers (renamed away by the compiler)
                cvx = nvx; cvy = nvy; cvx2 = nvx2; cvy2 = nvy2;
            }
        }
    }
}

extern "C" void kernel_launch(void* const* d_in, const int* in_sizes, int n_in,
                              void* d_out, int out_size, void* d_ws, size_t ws_size,
                              hipStream_t stream) {
    const float* img_out    = (const float*)d_in[0];
    const float* img_target = (const float*)d_in[1];
    // d_in[2] is window_size==11; fixed by the problem, baked into the kernel.
    float* out = (float*)d_out;

    dim3 grid(NS, NB / WPB, BC);   // 8 x 2 x 48 = 768 blocks, 4 waves each
    ssim_kernel<<<grid, 64 * WPB, 0, stream>>>(img_out, img_target, out);
}